// Round 11
// baseline (412.011 us; speedup 1.0000x reference)
//
#include <hip/hip_runtime.h>
#include <math.h>

// SoftclDiceLoss on (B,C,D,H,W) = (2,1,64,256,256) float32.
// R11: 3-blocks/CU pipeline. LDS = x ring4 (43.8 KB) + SINGLE srm (9.2 KB)
// = 53.0 KB -> 3 blocks/CU (12 waves). Two barriers per segment.
// Segment s:
//   commit x[s+2] (pending regs) ; issue x[s+3]
//   B(s):  mp[s] row r+1 in regs (12 b128 reads), rowmax -> srm (single buf)
//   xc:    x center of plane s-1 -> regs
//   -- barrier A --
//   H(s):  hw9[s] = max(srm rows r,r+2, register rowmax row r+1)
//   C(s-1): out[d=s-1] = relu(xc - (max(hw9[s-2],hw9[s-1],hw9[s]) - p1))
//   -- barrier B --
// Hazard audit:
//   srm RAW: B(s) writes pre-A, H(s) reads post-A.                   OK
//   srm WAR: H(s) reads pre-B_s; B(s+1) writes after B_s.            OK
//   x commit WAR: slot (s+2)&3 holds plane s-2, last read segment s-1
//     (xm of B(s-1), xc(s-2)) pre-A_{s-1}; commit at s is after
//     A_{s-1} and B_{s-1}.                                           OK
//   B(s) reads slots (s-1,s,s+1)&3; commit writes (s+2)&3: disjoint. OK
// Block 256 = 32 rows x 8 col-jobs (8 floats); tile 32x64; CD=8; grid
// 1024 = 2 tensors x 2b x 8 chunks x 8x4 tiles (both chains merged).

constexpr int Bn = 2;
constexpr int D  = 64;
constexpr int H  = 256;
constexpr int W  = 256;
constexpr int HW = H * W;           // 65536
constexpr int NV = Bn * D * H * W;  // 8388608

constexpr int CD  = 8;              // D-chunk per block
constexpr int XSF = 76;             // x LDS row stride (19 quads, odd)
constexpr int RSF = 68;             // rowmax LDS row stride (17 quads, odd)
// x plane: 36 rows (gh = h0-2+row), 18 quads (gw = w0-4+4q)
// rowmax:  34 rows (mp row mr, gh = h0-1+mr), cols = output cols w0..w0+63

__device__ __forceinline__ float4 vmin4(float4 a, float4 b) {
    return make_float4(fminf(a.x,b.x), fminf(a.y,b.y), fminf(a.z,b.z), fminf(a.w,b.w));
}
__device__ __forceinline__ float4 vmax4(float4 a, float4 b) {
    return make_float4(fmaxf(a.x,b.x), fmaxf(a.y,b.y), fmaxf(a.z,b.z), fmaxf(a.w,b.w));
}
__device__ __forceinline__ float4 sh1(float4 a, float4 b) { return make_float4(a.y,a.z,a.w,b.x); }
__device__ __forceinline__ float4 sh3(float4 a, float4 b) { return make_float4(a.w,b.x,b.y,b.z); }

__global__ __launch_bounds__(256) void prep_kernel(const float* __restrict__ logits,
                                                   const float* __restrict__ target,
                                                   const float* __restrict__ mask,
                                                   float* __restrict__ pred,
                                                   float* __restrict__ tgt) {
    int i = (blockIdx.x * 256 + threadIdx.x) * 4;
    float4 lg = *(const float4*)(logits + i);
    float4 tg = *(const float4*)(target + i);
    float4 mk = *(const float4*)(mask + i);
    float4 p, t;
    p.x = (1.0f/(1.0f+expf(-lg.x)))*mk.x;  t.x = tg.x*mk.x;
    p.y = (1.0f/(1.0f+expf(-lg.y)))*mk.y;  t.y = tg.y*mk.y;
    p.z = (1.0f/(1.0f+expf(-lg.z)))*mk.z;  t.z = tg.z*mk.z;
    p.w = (1.0f/(1.0f+expf(-lg.w)))*mk.w;  t.w = tg.w*mk.w;
    *(float4*)(pred + i) = p;
    *(float4*)(tgt + i)  = t;
}

template <bool FINAL>
__global__ __launch_bounds__(256) void skel_iter_kernel(
        const float* __restrict__ in0, float* __restrict__ out0,
        const float* __restrict__ oth0, double* __restrict__ acc0,
        const float* __restrict__ in1, float* __restrict__ out1,
        const float* __restrict__ oth1, double* __restrict__ acc1) {
    __shared__ float sx[4][36 * XSF];   // x ring of 4 (43.8 KB)
    __shared__ float srm[34 * RSF];     // rowmax, single buffer (9.2 KB)

    // XCD-chunked swizzle
    int cpx = gridDim.x >> 3;
    int hwb = blockIdx.x;
    int bx  = (hwb & 7) * cpx + (hwb >> 3);

    int t   = bx >> 9;                 // tensor select (0 when grid=512)
    int bt  = bx & 511;
    int w0  = (bt & 3) * 64;
    int h0  = ((bt >> 2) & 7) * 32;
    int gd0 = ((bt >> 5) & 7) * CD;
    int b   = (bt >> 8) & 1;

    const float* xin  = t ? in1  : in0;
    float*       xout = t ? out1 : out0;
    const float* oth  = t ? oth1 : oth0;
    double*      accp = t ? acc1 : acc0;

    int tid = threadIdx.x;
    int r   = tid >> 3;   // 0..31 output row
    int k   = tid & 7;    // 0..7  8-col job

    const float* xb  = xin + b * (D * HW);
    float*       ob  = xout ? (xout + b * (D * HW)) : nullptr;
    const float* otb = oth + b * (D * HW);

    const float4 INF4  = make_float4( INFINITY,  INFINITY,  INFINITY,  INFINITY);
    const float4 NINF4 = make_float4(-INFINITY, -INFINITY, -INFINITY, -INFINITY);

    // staging map: 648 quads (36 rows x 18), 3 rounds of 256
    int j1 = tid + 256, j2 = tid + 512;
    int sr0 = tid / 18, sq0 = tid - sr0 * 18;
    int sr1 = j1 / 18,  sq1 = j1 - sr1 * 18;
    int sr2 = j2 / 18,  sq2 = j2 - sr2 * 18;
    bool has2 = (j2 < 648);

    float4 Pa, Pb, Pc;   // pending plane
    auto issue = [&](int p) {
        if (p < 0 || p >= D) { Pa = Pb = Pc = INF4; return; }
        const float* pl = xb + p * HW;
        auto f = [&](int row, int qd) -> float4 {
            int gh = h0 - 2 + row;
            int gw = w0 - 4 + 4 * qd;
            if ((unsigned)gh < (unsigned)H && (unsigned)gw < (unsigned)W)
                return *(const float4*)(pl + gh * W + gw);
            return INF4;
        };
        Pa = f(sr0, sq0);
        Pb = f(sr1, sq1);
        Pc = has2 ? f(sr2, sq2) : INF4;
    };
    auto commitv = [&](int p, float4 va, float4 vb, float4 vc) {
        float* dst = sx[(p + 4) & 3];
        *(float4*)&dst[sr0 * XSF + 4 * sq0] = va;
        *(float4*)&dst[sr1 * XSF + 4 * sq1] = vb;
        if (has2) *(float4*)&dst[sr2 * XSF + 4 * sq2] = vc;
    };

    // Prologue: planes gd0-2..gd0 resident; x[gd0+1] pending.
    issue(gd0 - 2); commitv(gd0 - 2, Pa, Pb, Pc);
    issue(gd0 - 1); commitv(gd0 - 1, Pa, Pb, Pc);
    issue(gd0);     commitv(gd0,     Pa, Pb, Pc);
    issue(gd0 + 1);
    __syncthreads();

    float4 h1lo=NINF4, h1hi=NINF4, h2lo=NINF4, h2hi=NINF4;  // hw9[s-1], hw9[s-2]
    float4 p1lo=NINF4, p1hi=NINF4;                          // mp center of s-1
    double s0 = 0.0, s1 = 0.0;

    for (int s = gd0 - 1; s <= gd0 + CD; ++s) {
        // ---- staging: commit x[s+2] (captured), issue x[s+3] ----
        float4 Ta = Pa, Tb = Pb, Tc = Pc;
        if (s + 3 <= gd0 + CD + 1) issue(s + 3);
        if (s + 2 <= gd0 + CD + 1) commitv(s + 2, Ta, Tb, Tc);

        // ---- B(s): mp row r+1 in regs, rowmax -> srm ----
        bool sv = (s >= 0 && s < D);
        float4 lo = NINF4, hi = NINF4, rmlo = NINF4, rmhi = NINF4;
        if (sv) {
            const float* xq = sx[(s + 4) & 3];
            const float* xm = sx[(s + 3) & 3];
            const float* xp = sx[(s + 5) & 3];
            {
                const float* rc  = &xq[(r + 2) * XSF + 8 * k];
                const float* ru  = &xq[(r + 1) * XSF + 8 * k];
                const float* rd  = &xq[(r + 3) * XSF + 8 * k];
                const float* rm_ = &xm[(r + 2) * XSF + 8 * k];
                const float* rp_ = &xp[(r + 2) * XSF + 8 * k];
                float4 X0 = *(const float4*)rc,        X1 = *(const float4*)(rc + 4),
                       X2 = *(const float4*)(rc + 8),  X3 = *(const float4*)(rc + 12);
                float4 U1 = *(const float4*)(ru + 4),  U2 = *(const float4*)(ru + 8);
                float4 Dn1= *(const float4*)(rd + 4),  Dn2= *(const float4*)(rd + 8);
                float4 M1 = *(const float4*)(rm_ + 4), M2 = *(const float4*)(rm_ + 8);
                float4 P1 = *(const float4*)(rp_ + 4), P2 = *(const float4*)(rp_ + 8);
                lo = vmin4(vmin4(sh3(X0, X1), X1), sh1(X1, X2));
                lo = vmin4(lo, vmin4(vmin4(U1, Dn1), vmin4(M1, P1)));
                hi = vmin4(vmin4(sh3(X1, X2), X2), sh1(X2, X3));
                hi = vmin4(hi, vmin4(vmin4(U2, Dn2), vmin4(M2, P2)));
                float eL = __shfl_up(hi.w, 1);
                float eR = __shfl_down(lo.x, 1);
                if (k == 0) {
                    eL = -INFINITY;
                    if (w0 > 0) {
                        float w3 = fminf(fminf(X0.z, X0.w), X1.x);
                        eL = fminf(fminf(w3, fminf(ru[3], rd[3])),
                                   fminf(rm_[3], rp_[3]));
                    }
                }
                if (k == 7) {
                    eR = -INFINITY;
                    if (w0 + 64 < W) {
                        float w3 = fminf(fminf(X2.w, X3.x), X3.y);
                        eR = fminf(fminf(w3, fminf(ru[12], rd[12])),
                                   fminf(rm_[12], rp_[12]));
                    }
                }
                rmlo = vmax4(vmax4(make_float4(eL, lo.x, lo.y, lo.z), lo),
                             make_float4(lo.y, lo.z, lo.w, hi.x));
                rmhi = vmax4(vmax4(make_float4(lo.w, hi.x, hi.y, hi.z), hi),
                             make_float4(hi.y, hi.z, hi.w, eR));
                float* rw = &srm[(r + 1) * RSF + 8 * k];
                *(float4*)rw       = rmlo;
                *(float4*)(rw + 4) = rmhi;
            }
            if (tid < 16) {    // halo rows 0 and 33, fully in-thread
                int mr2 = (tid >> 3) ? 33 : 0;
                int k2  = tid & 7;
                int gh2 = h0 - 1 + mr2;
                float4 hlo = NINF4, hhi = NINF4;
                if ((unsigned)gh2 < (unsigned)H) {
                    int xr2 = mr2 + 1;
                    const float* rc  = &xq[xr2 * XSF + 8 * k2];
                    const float* ru  = &xq[(xr2 - 1) * XSF + 8 * k2];
                    const float* rd  = &xq[(xr2 + 1) * XSF + 8 * k2];
                    const float* rm_ = &xm[xr2 * XSF + 8 * k2];
                    const float* rp_ = &xp[xr2 * XSF + 8 * k2];
                    float4 X0 = *(const float4*)rc,        X1 = *(const float4*)(rc + 4),
                           X2 = *(const float4*)(rc + 8),  X3 = *(const float4*)(rc + 12);
                    float4 U1 = *(const float4*)(ru + 4),  U2 = *(const float4*)(ru + 8);
                    float4 Dn1= *(const float4*)(rd + 4),  Dn2= *(const float4*)(rd + 8);
                    float4 M1 = *(const float4*)(rm_ + 4), M2 = *(const float4*)(rm_ + 8);
                    float4 P1 = *(const float4*)(rp_ + 4), P2 = *(const float4*)(rp_ + 8);
                    float4 l2 = vmin4(vmin4(sh3(X0, X1), X1), sh1(X1, X2));
                    l2 = vmin4(l2, vmin4(vmin4(U1, Dn1), vmin4(M1, P1)));
                    float4 g2 = vmin4(vmin4(sh3(X1, X2), X2), sh1(X2, X3));
                    g2 = vmin4(g2, vmin4(vmin4(U2, Dn2), vmin4(M2, P2)));
                    float eL2 = -INFINITY, eR2 = -INFINITY;
                    if (w0 + 8 * k2 - 1 >= 0) {
                        float w3 = fminf(fminf(X0.z, X0.w), X1.x);
                        eL2 = fminf(fminf(w3, fminf(ru[3], rd[3])),
                                    fminf(rm_[3], rp_[3]));
                    }
                    if (w0 + 8 * k2 + 8 < W) {
                        float w3 = fminf(fminf(X2.w, X3.x), X3.y);
                        eR2 = fminf(fminf(w3, fminf(ru[12], rd[12])),
                                    fminf(rm_[12], rp_[12]));
                    }
                    hlo = vmax4(vmax4(make_float4(eL2, l2.x, l2.y, l2.z), l2),
                                make_float4(l2.y, l2.z, l2.w, g2.x));
                    hhi = vmax4(vmax4(make_float4(l2.w, g2.x, g2.y, g2.z), g2),
                                make_float4(g2.y, g2.z, g2.w, eR2));
                }
                float* hw = &srm[mr2 * RSF + 8 * k2];
                *(float4*)hw       = hlo;
                *(float4*)(hw + 4) = hhi;
            }
        }

        // ---- xc: x center of plane s-1 (slot (s+3)&3; commit wrote (s+2)&3) ----
        int d = s - 1;
        bool dv = (d >= gd0 && d <= gd0 + CD - 1);
        float4 xclo = INF4, xchi = INF4;
        if (dv) {
            const float* xd = sx[(s + 3) & 3];
            xclo = *(const float4*)&xd[(r + 2) * XSF + 8 * k + 4];
            xchi = *(const float4*)&xd[(r + 2) * XSF + 8 * k + 8];
        }

        __syncthreads();                                   // barrier A

        // ---- H(s): hw9[s] from srm rows r, r+2 + register row r+1 ----
        float4 hclo = NINF4, hchi = NINF4;
        if (sv) {
            float4 a0 = *(const float4*)&srm[r * RSF + 8 * k];
            float4 a1 = *(const float4*)&srm[r * RSF + 8 * k + 4];
            float4 b0 = *(const float4*)&srm[(r + 2) * RSF + 8 * k];
            float4 b1 = *(const float4*)&srm[(r + 2) * RSF + 8 * k + 4];
            hclo = vmax4(vmax4(a0, rmlo), b0);
            hchi = vmax4(vmax4(a1, rmhi), b1);
        }

        // ---- C(s-1): output d = s-1 ----
        if (dv) {
            float4 mxlo = vmax4(h2lo, vmax4(h1lo, hclo));
            float4 mxhi = vmax4(h2hi, vmax4(h1hi, hchi));
            float4 rlo, rhi;
            rlo.x = fmaxf(xclo.x - (mxlo.x - p1lo.x), 0.0f);
            rlo.y = fmaxf(xclo.y - (mxlo.y - p1lo.y), 0.0f);
            rlo.z = fmaxf(xclo.z - (mxlo.z - p1lo.z), 0.0f);
            rlo.w = fmaxf(xclo.w - (mxlo.w - p1lo.w), 0.0f);
            rhi.x = fmaxf(xchi.x - (mxhi.x - p1hi.x), 0.0f);
            rhi.y = fmaxf(xchi.y - (mxhi.y - p1hi.y), 0.0f);
            rhi.z = fmaxf(xchi.z - (mxhi.z - p1hi.z), 0.0f);
            rhi.w = fmaxf(xchi.w - (mxhi.w - p1hi.w), 0.0f);
            long off = (long)d * HW + (h0 + r) * W + (w0 + 8 * k);
            if constexpr (FINAL) {
                float4 o1 = *(const float4*)(otb + off);
                float4 o2 = *(const float4*)(otb + off + 4);
                s0 += (double)(rlo.x * o1.x) + (double)(rlo.y * o1.y)
                    + (double)(rlo.z * o1.z) + (double)(rlo.w * o1.w)
                    + (double)(rhi.x * o2.x) + (double)(rhi.y * o2.y)
                    + (double)(rhi.z * o2.z) + (double)(rhi.w * o2.w);
                s1 += (double)rlo.x + (double)rlo.y + (double)rlo.z + (double)rlo.w
                    + (double)rhi.x + (double)rhi.y + (double)rhi.z + (double)rhi.w;
            } else {
                *(float4*)(ob + off)     = rlo;
                *(float4*)(ob + off + 4) = rhi;
            }
        }

        // ---- shifts ----
        h2lo = h1lo; h2hi = h1hi; h1lo = hclo; h1hi = hchi;
        p1lo = lo;   p1hi = hi;

        __syncthreads();                                   // barrier B
    }

    if constexpr (FINAL) {
        for (int off = 32; off > 0; off >>= 1) {
            s0 += __shfl_down(s0, off, 64);
            s1 += __shfl_down(s1, off, 64);
        }
        if ((tid & 63) == 0) {
            atomicAdd(&accp[0], s0);
            atomicAdd(&accp[1], s1);
        }
    }
}

__global__ void final_kernel(const double* __restrict__ acc, float* __restrict__ out) {
    double clrecall = (acc[0] + 1e-12) / (acc[1] + 1e-12);
    double clacc    = (acc[2] + 1e-12) / (acc[3] + 1e-12);
    double cldice   = 2.0 * clrecall * clacc / (clrecall + clacc + 1e-12);
    out[0] = (float)(1.0 - cldice);
}

extern "C" void kernel_launch(void* const* d_in, const int* in_sizes, int n_in,
                              void* d_out, int out_size, void* d_ws, size_t ws_size,
                              hipStream_t stream) {
    const float* logits = (const float*)d_in[0];
    const float* target = (const float*)d_in[1];
    const float* mask   = (const float*)d_in[2];
    float* out = (float*)d_out;

    float* pred = (float*)d_ws;
    float* tgt  = pred + NV;
    float* A0   = tgt + NV;
    float* B0   = A0 + NV;

    bool big = ws_size >= (size_t)6 * NV * 4 + 64;
    float* A1   = big ? (B0 + NV) : A0;
    float* B1   = big ? (A1 + NV) : B0;
    double* acc = big ? (double*)(B1 + NV) : (double*)(B0 + NV);

    hipMemsetAsync(acc, 0, 4 * sizeof(double), stream);

    dim3 blk(256);
    prep_kernel<<<dim3(NV / 1024), blk, 0, stream>>>(logits, target, mask, pred, tgt);

    if (big) {
        dim3 g(1024);   // 2 tensors x 512 blocks; 3 blocks/CU capacity
        skel_iter_kernel<false><<<g, blk, 0, stream>>>(tgt, A0, pred, acc, pred, A1, tgt, acc + 2);
        skel_iter_kernel<false><<<g, blk, 0, stream>>>(A0, B0, pred, acc, A1, B1, tgt, acc + 2);
        skel_iter_kernel<false><<<g, blk, 0, stream>>>(B0, A0, pred, acc, B1, A1, tgt, acc + 2);
        skel_iter_kernel<false><<<g, blk, 0, stream>>>(A0, B0, pred, acc, A1, B1, tgt, acc + 2);
        skel_iter_kernel<true ><<<g, blk, 0, stream>>>(B0, nullptr, pred, acc, B1, nullptr, tgt, acc + 2);
    } else {
        dim3 g(512);    // sequential fallback (t = 0 always)
        skel_iter_kernel<false><<<g, blk, 0, stream>>>(tgt, A0, pred, acc, tgt, A0, pred, acc);
        skel_iter_kernel<false><<<g, blk, 0, stream>>>(A0, B0, pred, acc, A0, B0, pred, acc);
        skel_iter_kernel<false><<<g, blk, 0, stream>>>(B0, A0, pred, acc, B0, A0, pred, acc);
        skel_iter_kernel<false><<<g, blk, 0, stream>>>(A0, B0, pred, acc, A0, B0, pred, acc);
        skel_iter_kernel<true ><<<g, blk, 0, stream>>>(B0, nullptr, pred, acc, B0, nullptr, pred, acc);
        skel_iter_kernel<false><<<g, blk, 0, stream>>>(pred, A0, tgt, acc + 2, pred, A0, tgt, acc + 2);
        skel_iter_kernel<false><<<g, blk, 0, stream>>>(A0, B0, tgt, acc + 2, A0, B0, tgt, acc + 2);
        skel_iter_kernel<false><<<g, blk, 0, stream>>>(B0, A0, tgt, acc + 2, B0, A0, tgt, acc + 2);
        skel_iter_kernel<false><<<g, blk, 0, stream>>>(A0, B0, tgt, acc + 2, A0, B0, tgt, acc + 2);
        skel_iter_kernel<true ><<<g, blk, 0, stream>>>(B0, nullptr, tgt, acc + 2, B0, nullptr, tgt, acc + 2);
    }

    final_kernel<<<1, 1, 0, stream>>>(acc, out);
}

// Round 12
// 361.945 us; speedup vs baseline: 1.1383x; 1.1383x over previous
//
#include <hip/hip_runtime.h>
#include <math.h>

// SoftclDiceLoss on (B,C,D,H,W) = (2,1,64,256,256) float32.
// R12: R10's single-barrier pipeline + register-carried plane-(s-1) values
// -> x ring shrinks 4 to 3, LDS 62.3 -> 50.1 KB -> 3 blocks/CU, grid 768
// (exactly resident, no tail). Schedule per segment s (ONE barrier at end):
//   commit x[s+2] (pending regs) ; issue x[s+3]
//   B(s):  mp row r+1 in regs; xm operands = carried X1,X2 of B(s-1);
//          rowmax -> srm[s&1]
//   H(s-1): hw9 = max(srm[(s-1)&1] rows r,r+2, carried rowmax row r+1)
//   C(s-2): out = relu(XC - (max(h2,h1,hc) - p2)); XC = X1,X2 carried depth 2
// Hazard audit (ring 3):
//   B(s) reads slots s%3 (xq) and (s+1)%3 (xp); commit writes (s+2)%3:
//     all three distinct mod 3.                                      OK
//   commit x[s+2] overwrites plane s-1; plane s-1's last LDS readers:
//     B(s-1) (xq) and B(s-2) (xp) in earlier segments, barrier-separated;
//     segment-s uses of plane s-1 (xm, xc, edge scalars) are register
//     carries, never LDS.                                            OK
//   srm: B(s) writes [s&1], H(s-1) reads [(s-1)&1] (different buffer);
//     B(s+1)'s overwrite of [(s-1)&1] is after the end-of-s barrier.  OK
// Block 256 = 32 rows x 8 col-jobs (8 floats); tile 32x64; 6 uneven D-chunks
// (sizes 10/11); grid 768 = 2 tensors x 2b x 6 chunks x 32 tiles.

constexpr int Bn = 2;
constexpr int D  = 64;
constexpr int H  = 256;
constexpr int W  = 256;
constexpr int HW = H * W;           // 65536
constexpr int NV = Bn * D * H * W;  // 8388608

constexpr int XSF = 76;             // x LDS row stride (19 quads, odd)
constexpr int RSF = 68;             // rowmax LDS row stride (17 quads, odd)
// x plane: 36 rows (gh = h0-2+row), 18 quads (gw = w0-4+4q)
// rowmax:  34 rows (mp row mr, gh = h0-1+mr), cols = output cols w0..w0+63

__device__ __forceinline__ float4 vmin4(float4 a, float4 b) {
    return make_float4(fminf(a.x,b.x), fminf(a.y,b.y), fminf(a.z,b.z), fminf(a.w,b.w));
}
__device__ __forceinline__ float4 vmax4(float4 a, float4 b) {
    return make_float4(fmaxf(a.x,b.x), fmaxf(a.y,b.y), fmaxf(a.z,b.z), fmaxf(a.w,b.w));
}
__device__ __forceinline__ float4 sh1(float4 a, float4 b) { return make_float4(a.y,a.z,a.w,b.x); }
__device__ __forceinline__ float4 sh3(float4 a, float4 b) { return make_float4(a.w,b.x,b.y,b.z); }

__global__ __launch_bounds__(256) void prep_kernel(const float* __restrict__ logits,
                                                   const float* __restrict__ target,
                                                   const float* __restrict__ mask,
                                                   float* __restrict__ pred,
                                                   float* __restrict__ tgt) {
    int i = (blockIdx.x * 256 + threadIdx.x) * 4;
    float4 lg = *(const float4*)(logits + i);
    float4 tg = *(const float4*)(target + i);
    float4 mk = *(const float4*)(mask + i);
    float4 p, t;
    p.x = (1.0f/(1.0f+expf(-lg.x)))*mk.x;  t.x = tg.x*mk.x;
    p.y = (1.0f/(1.0f+expf(-lg.y)))*mk.y;  t.y = tg.y*mk.y;
    p.z = (1.0f/(1.0f+expf(-lg.z)))*mk.z;  t.z = tg.z*mk.z;
    p.w = (1.0f/(1.0f+expf(-lg.w)))*mk.w;  t.w = tg.w*mk.w;
    *(float4*)(pred + i) = p;
    *(float4*)(tgt + i)  = t;
}

template <bool FINAL>
__global__ __launch_bounds__(256) void skel_iter_kernel(
        const float* __restrict__ in0, float* __restrict__ out0,
        const float* __restrict__ oth0, double* __restrict__ acc0,
        const float* __restrict__ in1, float* __restrict__ out1,
        const float* __restrict__ oth1, double* __restrict__ acc1) {
    __shared__ float sx[3][36 * XSF];   // x ring of 3 (32.8 KB)
    __shared__ float srm[2][34 * RSF];  // rowmax ring of 2 (18.5 KB)

    // XCD-chunked swizzle (grid % 8 == 0)
    int cpx = gridDim.x >> 3;
    int hwb = blockIdx.x;
    int bx  = (hwb & 7) * cpx + (hwb >> 3);

    int t   = (bx >= 384) ? 1 : 0;     // tensor select (grid 384 -> always 0)
    int bt  = bx - 384 * t;
    int ti  = bt & 31;
    int w0  = (ti & 3) * 64;
    int h0  = (ti >> 2) * 32;
    int cc  = bt >> 5;                 // 0..11
    int b   = (cc >= 6) ? 1 : 0;
    int c   = cc - 6 * b;
    int gs  = (32 * c) / 3;            // chunk starts {0,10,21,32,42,53}
    int CDc = (32 * (c + 1)) / 3 - gs; // sizes {10,11,11,10,11,11}

    const float* xin  = t ? in1  : in0;
    float*       xout = t ? out1 : out0;
    const float* oth  = t ? oth1 : oth0;
    double*      accp = t ? acc1 : acc0;

    int tid = threadIdx.x;
    int r   = tid >> 3;   // 0..31 output row
    int k   = tid & 7;    // 0..7  8-col job

    const float* xb  = xin + b * (D * HW);
    float*       ob  = xout ? (xout + b * (D * HW)) : nullptr;
    const float* otb = oth + b * (D * HW);

    const float4 INF4  = make_float4( INFINITY,  INFINITY,  INFINITY,  INFINITY);
    const float4 NINF4 = make_float4(-INFINITY, -INFINITY, -INFINITY, -INFINITY);

    // staging map: 648 quads (36 rows x 18), 3 rounds of 256
    int j1 = tid + 256, j2 = tid + 512;
    int sr0 = tid / 18, sq0 = tid - sr0 * 18;
    int sr1 = j1 / 18,  sq1 = j1 - sr1 * 18;
    int sr2 = j2 / 18,  sq2 = j2 - sr2 * 18;
    bool has2 = (j2 < 648);

    float4 Pa, Pb, Pc;   // pending plane
    auto issue = [&](int p) {
        if (p < 0 || p >= D) { Pa = Pb = Pc = INF4; return; }
        const float* pl = xb + p * HW;
        auto f = [&](int row, int qd) -> float4 {
            int gh = h0 - 2 + row;
            int gw = w0 - 4 + 4 * qd;
            if ((unsigned)gh < (unsigned)H && (unsigned)gw < (unsigned)W)
                return *(const float4*)(pl + gh * W + gw);
            return INF4;
        };
        Pa = f(sr0, sq0);
        Pb = f(sr1, sq1);
        Pc = has2 ? f(sr2, sq2) : INF4;
    };
    auto commitv = [&](int p, float4 va, float4 vb, float4 vc) {
        float* dst = sx[(p + 6) % 3];
        *(float4*)&dst[sr0 * XSF + 4 * sq0] = va;
        *(float4*)&dst[sr1 * XSF + 4 * sq1] = vb;
        if (has2) *(float4*)&dst[sr2 * XSF + 4 * sq2] = vc;
    };

    // cross-min + W-rowmax for one 8-col job at x row `xrow`, job col `kk`.
    // Plane s-1 operands come from carries (cM1,cM2 = X1,X2; cx0w,cx3x).
    // Outputs new carries (raw X values of the current plane).
    auto crossrm = [&](const float* xq, const float* xp, int xrow, int kk,
                       bool rowOK, bool leftOK, bool rightOK,
                       float4 cM1, float4 cM2, float cx0w, float cx3x,
                       float4& lo, float4& hi, float4& rmlo, float4& rmhi,
                       float4& oX1, float4& oX2, float& ox0w, float& ox3x) {
        const float* rc = &xq[xrow * XSF + 8 * kk];
        const float* ru = rc - XSF;
        const float* rd = rc + XSF;
        const float* rp = &xp[xrow * XSF + 8 * kk];
        float4 X0 = *(const float4*)rc,       X1 = *(const float4*)(rc + 4),
               X2 = *(const float4*)(rc + 8), X3 = *(const float4*)(rc + 12);
        float4 U1 = *(const float4*)(ru + 4), U2 = *(const float4*)(ru + 8);
        float4 D1 = *(const float4*)(rd + 4), D2 = *(const float4*)(rd + 8);
        float4 P1 = *(const float4*)(rp + 4), P2 = *(const float4*)(rp + 8);
        oX1 = X1; oX2 = X2; ox0w = X0.w; ox3x = X3.x;
        lo = vmin4(vmin4(sh3(X0, X1), X1), sh1(X1, X2));
        lo = vmin4(lo, vmin4(vmin4(U1, D1), vmin4(cM1, P1)));
        hi = vmin4(vmin4(sh3(X1, X2), X2), sh1(X2, X3));
        hi = vmin4(hi, vmin4(vmin4(U2, D2), vmin4(cM2, P2)));
        float eL = __shfl_up(hi.w, 1);
        float eR = __shfl_down(lo.x, 1);
        if (kk == 0) {
            eL = -INFINITY;
            if (leftOK) {
                float w3 = fminf(fminf(X0.z, X0.w), X1.x);
                eL = fminf(fminf(w3, fminf(ru[3], rd[3])), fminf(cx0w, rp[3]));
            }
        }
        if (kk == 7) {
            eR = -INFINITY;
            if (rightOK) {
                float w3 = fminf(fminf(X2.w, X3.x), X3.y);
                eR = fminf(fminf(w3, fminf(ru[12], rd[12])), fminf(cx3x, rp[12]));
            }
        }
        if (!rowOK) { lo = NINF4; hi = NINF4; eL = -INFINITY; eR = -INFINITY; }
        rmlo = vmax4(vmax4(make_float4(eL, lo.x, lo.y, lo.z), lo),
                     make_float4(lo.y, lo.z, lo.w, hi.x));
        rmhi = vmax4(vmax4(make_float4(lo.w, hi.x, hi.y, hi.z), hi),
                     make_float4(hi.y, hi.z, hi.w, eR));
    };

    // ---- carry init from GLOBAL plane gs-2 (the plane not kept in LDS) ----
    float4 cM1 = INF4, cM2 = INF4;  float cx0w = INFINITY, cx3x = INFINITY;
    float4 hM1 = INF4, hM2 = INF4;  float hx0w = INFINITY, hx3x = INFINITY;
    {
        int p = gs - 2;
        if (p >= 0) {
            const float* pl = xb + p * HW;
            auto q = [&](int gh, int gw) -> float4 {
                if ((unsigned)gh < (unsigned)H && (unsigned)gw < (unsigned)W)
                    return *(const float4*)(pl + gh * W + gw);
                return INF4;
            };
            int gh = h0 + r;               // x row r+2 of the tile
            int gw = w0 - 4 + 8 * k;
            float4 X0 = q(gh, gw), X1 = q(gh, gw + 4),
                   X2 = q(gh, gw + 8), X3 = q(gh, gw + 12);
            cM1 = X1; cM2 = X2; cx0w = X0.w; cx3x = X3.x;
            if (tid < 16) {
                int mr2 = (tid >> 3) ? 33 : 0;
                int k2  = tid & 7;
                int gh2 = h0 - 2 + (mr2 + 1);
                int gw2 = w0 - 4 + 8 * k2;
                float4 Y0 = q(gh2, gw2), Y1 = q(gh2, gw2 + 4),
                       Y2 = q(gh2, gw2 + 8), Y3 = q(gh2, gw2 + 12);
                hM1 = Y1; hM2 = Y2; hx0w = Y0.w; hx3x = Y3.x;
            }
        }
    }

    // ---- prologue staging: planes gs-1, gs resident; gs+1 pending ----
    issue(gs - 1); commitv(gs - 1, Pa, Pb, Pc);
    issue(gs);     commitv(gs,     Pa, Pb, Pc);
    issue(gs + 1);
    __syncthreads();

    float4 h1lo=NINF4, h1hi=NINF4, h2lo=NINF4, h2hi=NINF4;  // hw9[s-2], hw9[s-3]
    float4 p1lo=NINF4, p1hi=NINF4, p2lo=NINF4, p2hi=NINF4;  // mp centers s-1, s-2
    float4 rmplo=NINF4, rmphi=NINF4;                        // rowmax row r+1 of s-1
    float4 XC1=INF4, XC2=INF4;                              // x center of plane s-2
    double s0 = 0.0, s1 = 0.0;

    for (int s = gs - 1; s <= gs + CDc + 1; ++s) {
        // ---- staging: commit x[s+2] (captured), issue x[s+3] ----
        float4 Ta = Pa, Tb = Pb, Tc = Pc;
        if (s + 3 <= gs + CDc + 1) issue(s + 3);
        if (s + 2 <= gs + CDc + 1) commitv(s + 2, Ta, Tb, Tc);

        // ---- B(s) ----
        bool sv = (s >= 0 && s < D && s <= gs + CDc);
        float4 lo = NINF4, hi = NINF4, rmlo = NINF4, rmhi = NINF4;
        float4 nM1 = INF4, nM2 = INF4;  float nx0w = INFINITY, nx3x = INFINITY;
        float4 nH1 = INF4, nH2 = INF4;  float nhx0w = INFINITY, nhx3x = INFINITY;
        if (sv) {
            const float* xq = sx[(s + 6) % 3];
            const float* xp = sx[(s + 7) % 3];
            crossrm(xq, xp, r + 2, k, true,
                    (w0 + 8 * k) > 0, (w0 + 8 * k + 8) < W,
                    cM1, cM2, cx0w, cx3x,
                    lo, hi, rmlo, rmhi, nM1, nM2, nx0w, nx3x);
            float* rw = &srm[s & 1][(r + 1) * RSF + 8 * k];
            *(float4*)rw       = rmlo;
            *(float4*)(rw + 4) = rmhi;
            if (tid < 16) {    // halo mp rows 0 and 33
                int mr2 = (tid >> 3) ? 33 : 0;
                int k2  = tid & 7;
                bool rowOK = (mr2 == 0) ? (h0 > 0) : (h0 + 32 < H);
                float4 qlo, qhi, qrmlo, qrmhi;
                crossrm(xq, xp, mr2 + 1, k2, rowOK,
                        (w0 + 8 * k2) > 0, (w0 + 8 * k2 + 8) < W,
                        hM1, hM2, hx0w, hx3x,
                        qlo, qhi, qrmlo, qrmhi, nH1, nH2, nhx0w, nhx3x);
                float* hw = &srm[s & 1][mr2 * RSF + 8 * k2];
                *(float4*)hw       = qrmlo;
                *(float4*)(hw + 4) = qrmhi;
            }
        }

        // ---- H(s-1): hw9 from srm[(s-1)&1] rows r, r+2 + carried rowmax ----
        int dm = s - 1;
        float4 hclo = NINF4, hchi = NINF4;
        if (s >= gs && dm >= 0 && dm < D) {
            const float* m = srm[dm & 1];
            float4 a0 = *(const float4*)&m[r * RSF + 8 * k];
            float4 a1 = *(const float4*)&m[r * RSF + 8 * k + 4];
            float4 b0 = *(const float4*)&m[(r + 2) * RSF + 8 * k];
            float4 b1 = *(const float4*)&m[(r + 2) * RSF + 8 * k + 4];
            hclo = vmax4(vmax4(a0, rmplo), b0);
            hchi = vmax4(vmax4(a1, rmphi), b1);
        }

        // ---- C(s-2): output d = s-2 (registers + global only) ----
        int d = s - 2;
        if (d >= gs && d <= gs + CDc - 1) {
            float4 mxlo = vmax4(h2lo, vmax4(h1lo, hclo));
            float4 mxhi = vmax4(h2hi, vmax4(h1hi, hchi));
            float4 rlo, rhi;
            rlo.x = fmaxf(XC1.x - (mxlo.x - p2lo.x), 0.0f);
            rlo.y = fmaxf(XC1.y - (mxlo.y - p2lo.y), 0.0f);
            rlo.z = fmaxf(XC1.z - (mxlo.z - p2lo.z), 0.0f);
            rlo.w = fmaxf(XC1.w - (mxlo.w - p2lo.w), 0.0f);
            rhi.x = fmaxf(XC2.x - (mxhi.x - p2hi.x), 0.0f);
            rhi.y = fmaxf(XC2.y - (mxhi.y - p2hi.y), 0.0f);
            rhi.z = fmaxf(XC2.z - (mxhi.z - p2hi.z), 0.0f);
            rhi.w = fmaxf(XC2.w - (mxhi.w - p2hi.w), 0.0f);
            long off = (long)d * HW + (h0 + r) * W + (w0 + 8 * k);
            if constexpr (FINAL) {
                float4 o1 = *(const float4*)(otb + off);
                float4 o2 = *(const float4*)(otb + off + 4);
                s0 += (double)(rlo.x * o1.x) + (double)(rlo.y * o1.y)
                    + (double)(rlo.z * o1.z) + (double)(rlo.w * o1.w)
                    + (double)(rhi.x * o2.x) + (double)(rhi.y * o2.y)
                    + (double)(rhi.z * o2.z) + (double)(rhi.w * o2.w);
                s1 += (double)rlo.x + (double)rlo.y + (double)rlo.z + (double)rlo.w
                    + (double)rhi.x + (double)rhi.y + (double)rhi.z + (double)rhi.w;
            } else {
                *(float4*)(ob + off)     = rlo;
                *(float4*)(ob + off + 4) = rhi;
            }
        }

        // ---- shifts (XC gets OLD cM before cM updates: depth-2 chain) ----
        h2lo = h1lo; h2hi = h1hi; h1lo = hclo; h1hi = hchi;
        p2lo = p1lo; p2hi = p1hi; p1lo = lo;   p1hi = hi;
        rmplo = rmlo; rmphi = rmhi;
        XC1 = cM1; XC2 = cM2;
        cM1 = nM1; cM2 = nM2; cx0w = nx0w; cx3x = nx3x;
        hM1 = nH1; hM2 = nH2; hx0w = nhx0w; hx3x = nhx3x;

        __syncthreads();   // the ONLY barrier per segment
    }

    if constexpr (FINAL) {
        for (int off = 32; off > 0; off >>= 1) {
            s0 += __shfl_down(s0, off, 64);
            s1 += __shfl_down(s1, off, 64);
        }
        if ((tid & 63) == 0) {
            atomicAdd(&accp[0], s0);
            atomicAdd(&accp[1], s1);
        }
    }
}

__global__ void final_kernel(const double* __restrict__ acc, float* __restrict__ out) {
    double clrecall = (acc[0] + 1e-12) / (acc[1] + 1e-12);
    double clacc    = (acc[2] + 1e-12) / (acc[3] + 1e-12);
    double cldice   = 2.0 * clrecall * clacc / (clrecall + clacc + 1e-12);
    out[0] = (float)(1.0 - cldice);
}

extern "C" void kernel_launch(void* const* d_in, const int* in_sizes, int n_in,
                              void* d_out, int out_size, void* d_ws, size_t ws_size,
                              hipStream_t stream) {
    const float* logits = (const float*)d_in[0];
    const float* target = (const float*)d_in[1];
    const float* mask   = (const float*)d_in[2];
    float* out = (float*)d_out;

    float* pred = (float*)d_ws;
    float* tgt  = pred + NV;
    float* A0   = tgt + NV;
    float* B0   = A0 + NV;

    bool big = ws_size >= (size_t)6 * NV * 4 + 64;
    float* A1   = big ? (B0 + NV) : A0;
    float* B1   = big ? (A1 + NV) : B0;
    double* acc = big ? (double*)(B1 + NV) : (double*)(B0 + NV);

    hipMemsetAsync(acc, 0, 4 * sizeof(double), stream);

    dim3 blk(256);
    prep_kernel<<<dim3(NV / 1024), blk, 0, stream>>>(logits, target, mask, pred, tgt);

    if (big) {
        dim3 g(768);   // 2 tensors x 384; 3 blocks/CU -> exactly resident
        skel_iter_kernel<false><<<g, blk, 0, stream>>>(tgt, A0, pred, acc, pred, A1, tgt, acc + 2);
        skel_iter_kernel<false><<<g, blk, 0, stream>>>(A0, B0, pred, acc, A1, B1, tgt, acc + 2);
        skel_iter_kernel<false><<<g, blk, 0, stream>>>(B0, A0, pred, acc, B1, A1, tgt, acc + 2);
        skel_iter_kernel<false><<<g, blk, 0, stream>>>(A0, B0, pred, acc, A1, B1, tgt, acc + 2);
        skel_iter_kernel<true ><<<g, blk, 0, stream>>>(B0, nullptr, pred, acc, B1, nullptr, tgt, acc + 2);
    } else {
        dim3 g(384);   // sequential fallback (t = 0 always)
        skel_iter_kernel<false><<<g, blk, 0, stream>>>(tgt, A0, pred, acc, tgt, A0, pred, acc);
        skel_iter_kernel<false><<<g, blk, 0, stream>>>(A0, B0, pred, acc, A0, B0, pred, acc);
        skel_iter_kernel<false><<<g, blk, 0, stream>>>(B0, A0, pred, acc, B0, A0, pred, acc);
        skel_iter_kernel<false><<<g, blk, 0, stream>>>(A0, B0, pred, acc, A0, B0, pred, acc);
        skel_iter_kernel<true ><<<g, blk, 0, stream>>>(B0, nullptr, pred, acc, B0, nullptr, pred, acc);
        skel_iter_kernel<false><<<g, blk, 0, stream>>>(pred, A0, tgt, acc + 2, pred, A0, tgt, acc + 2);
        skel_iter_kernel<false><<<g, blk, 0, stream>>>(A0, B0, tgt, acc + 2, A0, B0, tgt, acc + 2);
        skel_iter_kernel<false><<<g, blk, 0, stream>>>(B0, A0, tgt, acc + 2, B0, A0, tgt, acc + 2);
        skel_iter_kernel<false><<<g, blk, 0, stream>>>(A0, B0, tgt, acc + 2, A0, B0, tgt, acc + 2);
        skel_iter_kernel<true ><<<g, blk, 0, stream>>>(B0, nullptr, tgt, acc + 2, B0, nullptr, tgt, acc + 2);
    }

    final_kernel<<<1, 1, 0, stream>>>(acc, out);
}

// Round 13
// 349.785 us; speedup vs baseline: 1.1779x; 1.0348x over previous
//
#include <hip/hip_runtime.h>
#include <math.h>

// SoftclDiceLoss on (B,C,D,H,W) = (2,1,64,256,256) float32.
// R13 = R10's proven geometry/schedule (CD=16, grid 512, x ring-4, srm ring-2,
// ONE barrier per segment, merged chains) + two traffic cuts:
//  (1) prep folded into staging/FINAL via wave-uniform mode functor:
//      mode 0: x = A[i] ; mode 1: x = A[i]*B[i] ; mode 2: x = sigmoid(A[i])*B[i]
//      -> no prep kernel, no pred/tgt buffers.
//  (2) register carries (validated in R12) for plane s-1 operands:
//      xm quads (cM1,cM2), xc center (XC, depth-2), edge scalars (cx0w,cx3x)
//      -> 4 fewer b128 LDS reads per thread-segment; ring stays 4 (schedule
//      and hazard audit identical to R10, now strictly weaker requirements).
// Segment s: commit x[s+2]; issue x[s+3]; B(s): mp row r+1 in regs ->
// rowmax -> srm[s&1]; H(s-1): hw9 from srm[(s-1)&1] rows r,r+2 + carried
// rowmax; C(s-2): out = relu(XC - (max(h2,h1,hc) - p2)); ONE barrier.

constexpr int Bn = 2;
constexpr int D  = 64;
constexpr int H  = 256;
constexpr int W  = 256;
constexpr int HW = H * W;           // 65536
constexpr int NV = Bn * D * H * W;  // 8388608

constexpr int CD  = 16;             // D-chunk per block
constexpr int XSF = 76;             // x LDS row stride (19 quads, odd)
constexpr int RSF = 68;             // rowmax LDS row stride (17 quads, odd)
// x plane: 36 rows (gh = h0-2+row), 18 quads (gw = w0-4+4q)
// rowmax:  34 rows (mp row mr, gh = h0-1+mr), cols = output cols w0..w0+63

__device__ __forceinline__ float4 vmin4(float4 a, float4 b) {
    return make_float4(fminf(a.x,b.x), fminf(a.y,b.y), fminf(a.z,b.z), fminf(a.w,b.w));
}
__device__ __forceinline__ float4 vmax4(float4 a, float4 b) {
    return make_float4(fmaxf(a.x,b.x), fmaxf(a.y,b.y), fmaxf(a.z,b.z), fmaxf(a.w,b.w));
}
__device__ __forceinline__ float4 sh1(float4 a, float4 b) { return make_float4(a.y,a.z,a.w,b.x); }
__device__ __forceinline__ float4 sh3(float4 a, float4 b) { return make_float4(a.w,b.x,b.y,b.z); }

// mode 0: a ; mode 1: a*b ; mode 2: sigmoid(a)*b   (mode is wave-uniform)
__device__ __forceinline__ float4 apply_mode(float4 a, const float* __restrict__ pb,
                                             long ix, int mode) {
    if (mode != 0) {
        if (mode == 2) {
            a.x = 1.0f / (1.0f + expf(-a.x));
            a.y = 1.0f / (1.0f + expf(-a.y));
            a.z = 1.0f / (1.0f + expf(-a.z));
            a.w = 1.0f / (1.0f + expf(-a.w));
        }
        float4 m = *(const float4*)(pb + ix);
        a.x *= m.x; a.y *= m.y; a.z *= m.z; a.w *= m.w;
    }
    return a;
}

template <bool FINAL>
__global__ __launch_bounds__(256) void skel_iter_kernel(
        const float* __restrict__ iA0, const float* __restrict__ iB0, int im0,
        float* __restrict__ out0,
        const float* __restrict__ oA0, const float* __restrict__ oB0, int om0,
        double* __restrict__ acc0,
        const float* __restrict__ iA1, const float* __restrict__ iB1, int im1,
        float* __restrict__ out1,
        const float* __restrict__ oA1, const float* __restrict__ oB1, int om1,
        double* __restrict__ acc1) {
    __shared__ float sx[4][36 * XSF];   // x ring of 4 (43.8 KB)
    __shared__ float srm[2][34 * RSF];  // rowmax ring of 2 (18.5 KB)

    // XCD-chunked swizzle
    int cpx = gridDim.x >> 3;
    int hwb = blockIdx.x;
    int bx  = (hwb & 7) * cpx + (hwb >> 3);

    int t   = bx >> 8;                 // tensor select (0 when grid=256)
    int bt  = bx & 255;
    int w0  = (bt & 3) * 64;
    int h0  = ((bt >> 2) & 7) * 32;
    int gd0 = ((bt >> 5) & 3) * CD;
    int b   = (bt >> 7) & 1;

    const float* iA = t ? iA1 : iA0;
    const float* iB = t ? iB1 : iB0;
    int          im = t ? im1 : im0;
    float*     xout = t ? out1 : out0;
    const float* oA = t ? oA1 : oA0;
    const float* oB = t ? oB1 : oB0;
    int          om = t ? om1 : om0;
    double*    accp = t ? acc1 : acc0;

    long base = (long)b * (D * HW);
    const float* xbA = iA + base;
    const float* xbB = iB ? iB + base : nullptr;
    float*       ob  = xout ? xout + base : nullptr;
    const float* obA = oA ? oA + base : nullptr;
    const float* obB = oB ? oB + base : nullptr;

    int tid = threadIdx.x;
    int r   = tid >> 3;   // 0..31 output row
    int k   = tid & 7;    // 0..7  8-col job

    const float4 INF4  = make_float4( INFINITY,  INFINITY,  INFINITY,  INFINITY);
    const float4 NINF4 = make_float4(-INFINITY, -INFINITY, -INFINITY, -INFINITY);

    // staging map: 648 quads (36 rows x 18), 3 rounds of 256
    int j1 = tid + 256, j2 = tid + 512;
    int sr0 = tid / 18, sq0 = tid - sr0 * 18;
    int sr1 = j1 / 18,  sq1 = j1 - sr1 * 18;
    int sr2 = j2 / 18,  sq2 = j2 - sr2 * 18;
    bool has2 = (j2 < 648);

    float4 Pa, Pb, Pc;   // pending plane
    auto issue = [&](int p) {
        if (p < 0 || p >= D) { Pa = Pb = Pc = INF4; return; }
        long pb = (long)p * HW;
        auto f = [&](int row, int qd) -> float4 {
            int gh = h0 - 2 + row;
            int gw = w0 - 4 + 4 * qd;
            if ((unsigned)gh < (unsigned)H && (unsigned)gw < (unsigned)W) {
                long ix = pb + gh * W + gw;
                float4 a = *(const float4*)(xbA + ix);
                return apply_mode(a, xbB, ix, im);
            }
            return INF4;
        };
        Pa = f(sr0, sq0);
        Pb = f(sr1, sq1);
        Pc = has2 ? f(sr2, sq2) : INF4;
    };
    auto commitv = [&](int p, float4 va, float4 vb, float4 vc) {
        float* dst = sx[(p + 4) & 3];
        *(float4*)&dst[sr0 * XSF + 4 * sq0] = va;
        *(float4*)&dst[sr1 * XSF + 4 * sq1] = vb;
        if (has2) *(float4*)&dst[sr2 * XSF + 4 * sq2] = vc;
    };

    // Prologue: planes gd0-2..gd0 resident; x[gd0+1] pending.
    issue(gd0 - 2); commitv(gd0 - 2, Pa, Pb, Pc);
    issue(gd0 - 1); commitv(gd0 - 1, Pa, Pb, Pc);
    issue(gd0);     commitv(gd0,     Pa, Pb, Pc);
    issue(gd0 + 1);
    __syncthreads();

    // Carry seed from LDS plane gd0-2 (slot (gd0+2)&3; that slot is first
    // overwritten by commit at segment s=gd0, two barriers after these reads).
    float4 cM1, cM2;  float cx0w, cx3x;             // xm quads / edges, plane s-1
    float4 hM1 = INF4, hM2 = INF4;  float hx0w = INFINITY, hx3x = INFINITY;
    {
        const float* x2 = sx[(gd0 + 2) & 3];
        const float* rc = &x2[(r + 2) * XSF + 8 * k];
        float4 X0 = *(const float4*)rc,       X1 = *(const float4*)(rc + 4),
               X2v = *(const float4*)(rc + 8), X3 = *(const float4*)(rc + 12);
        cM1 = X1; cM2 = X2v; cx0w = X0.w; cx3x = X3.x;
        if (tid < 16) {
            int mr2 = (tid >> 3) ? 33 : 0;
            int k2  = tid & 7;
            const float* hcp = &x2[(mr2 + 1) * XSF + 8 * k2];
            float4 Y0 = *(const float4*)hcp,       Y1 = *(const float4*)(hcp + 4),
                   Y2 = *(const float4*)(hcp + 8), Y3 = *(const float4*)(hcp + 12);
            hM1 = Y1; hM2 = Y2; hx0w = Y0.w; hx3x = Y3.x;
        }
    }

    float4 h1lo=NINF4, h1hi=NINF4, h2lo=NINF4, h2hi=NINF4;  // hw9 ring
    float4 p1lo=NINF4, p1hi=NINF4, p2lo=NINF4, p2hi=NINF4;  // mp centers s-1, s-2
    float4 rmplo=NINF4, rmphi=NINF4;                        // rowmax row r+1 of s-1
    float4 XC1=INF4, XC2=INF4;                              // x center of plane s-2
    double s0 = 0.0, s1 = 0.0;

    for (int s = gd0 - 1; s <= gd0 + CD + 1; ++s) {
        // ---- staging: commit x[s+2] (captured), issue x[s+3] ----
        float4 Ta = Pa, Tb = Pb, Tc = Pc;
        if (s + 3 <= gd0 + CD + 1) issue(s + 3);
        if (s + 2 <= gd0 + CD + 1) commitv(s + 2, Ta, Tb, Tc);

        // ---- B(s): mp row r+1 in regs (10 b128 reads), rowmax -> srm[s&1] ----
        bool sv = (s >= 0 && s < D);
        float4 lo = NINF4, hi = NINF4, rmlo = NINF4, rmhi = NINF4;
        float4 nM1 = INF4, nM2 = INF4;  float nx0w = INFINITY, nx3x = INFINITY;
        float4 nH1 = INF4, nH2 = INF4;  float nhx0w = INFINITY, nhx3x = INFINITY;
        if (sv) {
            const float* xq = sx[(s + 4) & 3];
            const float* xp = sx[(s + 5) & 3];
            {
                const float* rc = &xq[(r + 2) * XSF + 8 * k];
                const float* ru = rc - XSF;
                const float* rd = rc + XSF;
                const float* rp = &xp[(r + 2) * XSF + 8 * k];
                float4 X0 = *(const float4*)rc,        X1 = *(const float4*)(rc + 4),
                       X2v = *(const float4*)(rc + 8), X3 = *(const float4*)(rc + 12);
                float4 U1 = *(const float4*)(ru + 4),  U2 = *(const float4*)(ru + 8);
                float4 D1 = *(const float4*)(rd + 4),  D2 = *(const float4*)(rd + 8);
                float4 P1 = *(const float4*)(rp + 4),  P2 = *(const float4*)(rp + 8);
                nM1 = X1; nM2 = X2v; nx0w = X0.w; nx3x = X3.x;
                lo = vmin4(vmin4(sh3(X0, X1), X1), sh1(X1, X2v));
                lo = vmin4(lo, vmin4(vmin4(U1, D1), vmin4(cM1, P1)));
                hi = vmin4(vmin4(sh3(X1, X2v), X2v), sh1(X2v, X3));
                hi = vmin4(hi, vmin4(vmin4(U2, D2), vmin4(cM2, P2)));
                float eL = __shfl_up(hi.w, 1);
                float eR = __shfl_down(lo.x, 1);
                if (k == 0) {
                    eL = -INFINITY;
                    if (w0 > 0) {
                        float w3 = fminf(fminf(X0.z, X0.w), X1.x);
                        eL = fminf(fminf(w3, fminf(ru[3], rd[3])),
                                   fminf(cx0w, rp[3]));
                    }
                }
                if (k == 7) {
                    eR = -INFINITY;
                    if (w0 + 64 < W) {
                        float w3 = fminf(fminf(X2v.w, X3.x), X3.y);
                        eR = fminf(fminf(w3, fminf(ru[12], rd[12])),
                                   fminf(cx3x, rp[12]));
                    }
                }
                rmlo = vmax4(vmax4(make_float4(eL, lo.x, lo.y, lo.z), lo),
                             make_float4(lo.y, lo.z, lo.w, hi.x));
                rmhi = vmax4(vmax4(make_float4(lo.w, hi.x, hi.y, hi.z), hi),
                             make_float4(hi.y, hi.z, hi.w, eR));
                float* rw = &srm[s & 1][(r + 1) * RSF + 8 * k];
                *(float4*)rw       = rmlo;
                *(float4*)(rw + 4) = rmhi;
            }
            if (tid < 16) {    // halo mp rows 0 and 33
                int mr2 = (tid >> 3) ? 33 : 0;
                int k2  = tid & 7;
                int gh2 = h0 - 1 + mr2;
                int xr2 = mr2 + 1;
                const float* rc = &xq[xr2 * XSF + 8 * k2];
                const float* ru = rc - XSF;
                const float* rd = rc + XSF;
                const float* rp = &xp[xr2 * XSF + 8 * k2];
                float4 X0 = *(const float4*)rc,        X1 = *(const float4*)(rc + 4),
                       X2v = *(const float4*)(rc + 8), X3 = *(const float4*)(rc + 12);
                float4 U1 = *(const float4*)(ru + 4),  U2 = *(const float4*)(ru + 8);
                float4 D1 = *(const float4*)(rd + 4),  D2 = *(const float4*)(rd + 8);
                float4 P1 = *(const float4*)(rp + 4),  P2 = *(const float4*)(rp + 8);
                nH1 = X1; nH2 = X2v; nhx0w = X0.w; nhx3x = X3.x;
                float4 hlo = NINF4, hhi = NINF4;
                if ((unsigned)gh2 < (unsigned)H) {
                    float4 l2 = vmin4(vmin4(sh3(X0, X1), X1), sh1(X1, X2v));
                    l2 = vmin4(l2, vmin4(vmin4(U1, D1), vmin4(hM1, P1)));
                    float4 g2 = vmin4(vmin4(sh3(X1, X2v), X2v), sh1(X2v, X3));
                    g2 = vmin4(g2, vmin4(vmin4(U2, D2), vmin4(hM2, P2)));
                    float eL2 = -INFINITY, eR2 = -INFINITY;
                    if (w0 + 8 * k2 - 1 >= 0) {
                        float w3 = fminf(fminf(X0.z, X0.w), X1.x);
                        eL2 = fminf(fminf(w3, fminf(ru[3], rd[3])),
                                    fminf(hx0w, rp[3]));
                    }
                    if (w0 + 8 * k2 + 8 < W) {
                        float w3 = fminf(fminf(X2v.w, X3.x), X3.y);
                        eR2 = fminf(fminf(w3, fminf(ru[12], rd[12])),
                                    fminf(hx3x, rp[12]));
                    }
                    hlo = vmax4(vmax4(make_float4(eL2, l2.x, l2.y, l2.z), l2),
                                make_float4(l2.y, l2.z, l2.w, g2.x));
                    hhi = vmax4(vmax4(make_float4(l2.w, g2.x, g2.y, g2.z), g2),
                                make_float4(g2.y, g2.z, g2.w, eR2));
                }
                float* hw = &srm[s & 1][mr2 * RSF + 8 * k2];
                *(float4*)hw       = hlo;
                *(float4*)(hw + 4) = hhi;
            }
        }

        // ---- H(s-1): hw9 from srm[(s-1)&1] rows r, r+2 + carried rowmax ----
        int dm = s - 1;
        float4 hclo = NINF4, hchi = NINF4;
        if (s >= gd0 && dm >= 0 && dm < D) {
            const float* m = srm[dm & 1];
            float4 a0 = *(const float4*)&m[r * RSF + 8 * k];
            float4 a1 = *(const float4*)&m[r * RSF + 8 * k + 4];
            float4 b0 = *(const float4*)&m[(r + 2) * RSF + 8 * k];
            float4 b1 = *(const float4*)&m[(r + 2) * RSF + 8 * k + 4];
            hclo = vmax4(vmax4(a0, rmplo), b0);
            hchi = vmax4(vmax4(a1, rmphi), b1);
        }

        // ---- C(s-2): output d = s-2 (registers + global only) ----
        int d = s - 2;
        if (d >= gd0 && d <= gd0 + CD - 1) {
            float4 mxlo = vmax4(h2lo, vmax4(h1lo, hclo));
            float4 mxhi = vmax4(h2hi, vmax4(h1hi, hchi));
            float4 rlo, rhi;
            rlo.x = fmaxf(XC1.x - (mxlo.x - p2lo.x), 0.0f);
            rlo.y = fmaxf(XC1.y - (mxlo.y - p2lo.y), 0.0f);
            rlo.z = fmaxf(XC1.z - (mxlo.z - p2lo.z), 0.0f);
            rlo.w = fmaxf(XC1.w - (mxlo.w - p2lo.w), 0.0f);
            rhi.x = fmaxf(XC2.x - (mxhi.x - p2hi.x), 0.0f);
            rhi.y = fmaxf(XC2.y - (mxhi.y - p2hi.y), 0.0f);
            rhi.z = fmaxf(XC2.z - (mxhi.z - p2hi.z), 0.0f);
            rhi.w = fmaxf(XC2.w - (mxhi.w - p2hi.w), 0.0f);
            long off = (long)d * HW + (h0 + r) * W + (w0 + 8 * k);
            if constexpr (FINAL) {
                float4 o1 = *(const float4*)(obA + off);
                o1 = apply_mode(o1, obB, off, om);
                float4 o2 = *(const float4*)(obA + off + 4);
                o2 = apply_mode(o2, obB, off + 4, om);
                s0 += (double)(rlo.x * o1.x) + (double)(rlo.y * o1.y)
                    + (double)(rlo.z * o1.z) + (double)(rlo.w * o1.w)
                    + (double)(rhi.x * o2.x) + (double)(rhi.y * o2.y)
                    + (double)(rhi.z * o2.z) + (double)(rhi.w * o2.w);
                s1 += (double)rlo.x + (double)rlo.y + (double)rlo.z + (double)rlo.w
                    + (double)rhi.x + (double)rhi.y + (double)rhi.z + (double)rhi.w;
            } else {
                *(float4*)(ob + off)     = rlo;
                *(float4*)(ob + off + 4) = rhi;
            }
        }

        // ---- shifts (XC takes OLD cM before cM updates: depth-2 chain) ----
        h2lo = h1lo; h2hi = h1hi; h1lo = hclo; h1hi = hchi;
        p2lo = p1lo; p2hi = p1hi; p1lo = lo;   p1hi = hi;
        rmplo = rmlo; rmphi = rmhi;
        XC1 = cM1; XC2 = cM2;
        cM1 = nM1; cM2 = nM2; cx0w = nx0w; cx3x = nx3x;
        hM1 = nH1; hM2 = nH2; hx0w = nhx0w; hx3x = nhx3x;

        __syncthreads();   // the ONLY barrier per segment
    }

    if constexpr (FINAL) {
        for (int off = 32; off > 0; off >>= 1) {
            s0 += __shfl_down(s0, off, 64);
            s1 += __shfl_down(s1, off, 64);
        }
        if ((tid & 63) == 0) {
            atomicAdd(&accp[0], s0);
            atomicAdd(&accp[1], s1);
        }
    }
}

__global__ void final_kernel(const double* __restrict__ acc, float* __restrict__ out) {
    double clrecall = (acc[0] + 1e-12) / (acc[1] + 1e-12);
    double clacc    = (acc[2] + 1e-12) / (acc[3] + 1e-12);
    double cldice   = 2.0 * clrecall * clacc / (clrecall + clacc + 1e-12);
    out[0] = (float)(1.0 - cldice);
}

extern "C" void kernel_launch(void* const* d_in, const int* in_sizes, int n_in,
                              void* d_out, int out_size, void* d_ws, size_t ws_size,
                              hipStream_t stream) {
    const float* logits = (const float*)d_in[0];
    const float* target = (const float*)d_in[1];
    const float* mask   = (const float*)d_in[2];
    float* out = (float*)d_out;

    // Workspace (floats): A0 | B0 | A1 | B1 | acc(4 doubles)
    float* A0 = (float*)d_ws;
    float* B0 = A0 + NV;

    bool big = ws_size >= (size_t)4 * NV * 4 + 64;
    float* A1   = big ? (B0 + NV) : A0;
    float* B1   = big ? (A1 + NV) : B0;
    double* acc = big ? (double*)(B1 + NV) : (double*)(B0 + NV);

    hipMemsetAsync(acc, 0, 4 * sizeof(double), stream);

    dim3 blk(256);
    const float* Z = nullptr;

    if (big) {
        dim3 g(512);   // 2 tensors x 256 blocks; 2 blocks/CU, all resident
        // chain0: skel(target*mask); chain1: skel(sigmoid(logits)*mask)
        skel_iter_kernel<false><<<g, blk, 0, stream>>>(
            target, mask, 1, A0, Z, Z, 0, acc,
            logits, mask, 2, A1, Z, Z, 0, acc + 2);
        skel_iter_kernel<false><<<g, blk, 0, stream>>>(
            A0, Z, 0, B0, Z, Z, 0, acc,
            A1, Z, 0, B1, Z, Z, 0, acc + 2);
        skel_iter_kernel<false><<<g, blk, 0, stream>>>(
            B0, Z, 0, A0, Z, Z, 0, acc,
            B1, Z, 0, A1, Z, Z, 0, acc + 2);
        skel_iter_kernel<false><<<g, blk, 0, stream>>>(
            A0, Z, 0, B0, Z, Z, 0, acc,
            A1, Z, 0, B1, Z, Z, 0, acc + 2);
        // FINAL: chain0 vs pred (mode 2), chain1 vs tgt (mode 1)
        skel_iter_kernel<true><<<g, blk, 0, stream>>>(
            B0, Z, 0, nullptr, logits, mask, 2, acc,
            B1, Z, 0, nullptr, target, mask, 1, acc + 2);
    } else {
        dim3 g(256);   // sequential fallback (t = 0 always)
        skel_iter_kernel<false><<<g, blk, 0, stream>>>(
            target, mask, 1, A0, Z, Z, 0, acc,
            target, mask, 1, A0, Z, Z, 0, acc);
        skel_iter_kernel<false><<<g, blk, 0, stream>>>(
            A0, Z, 0, B0, Z, Z, 0, acc, A0, Z, 0, B0, Z, Z, 0, acc);
        skel_iter_kernel<false><<<g, blk, 0, stream>>>(
            B0, Z, 0, A0, Z, Z, 0, acc, B0, Z, 0, A0, Z, Z, 0, acc);
        skel_iter_kernel<false><<<g, blk, 0, stream>>>(
            A0, Z, 0, B0, Z, Z, 0, acc, A0, Z, 0, B0, Z, Z, 0, acc);
        skel_iter_kernel<true><<<g, blk, 0, stream>>>(
            B0, Z, 0, nullptr, logits, mask, 2, acc,
            B0, Z, 0, nullptr, logits, mask, 2, acc);
        skel_iter_kernel<false><<<g, blk, 0, stream>>>(
            logits, mask, 2, A0, Z, Z, 0, acc + 2,
            logits, mask, 2, A0, Z, Z, 0, acc + 2);
        skel_iter_kernel<false><<<g, blk, 0, stream>>>(
            A0, Z, 0, B0, Z, Z, 0, acc + 2, A0, Z, 0, B0, Z, Z, 0, acc + 2);
        skel_iter_kernel<false><<<g, blk, 0, stream>>>(
            B0, Z, 0, A0, Z, Z, 0, acc + 2, B0, Z, 0, A0, Z, Z, 0, acc + 2);
        skel_iter_kernel<false><<<g, blk, 0, stream>>>(
            A0, Z, 0, B0, Z, Z, 0, acc + 2, A0, Z, 0, B0, Z, Z, 0, acc + 2);
        skel_iter_kernel<true><<<g, blk, 0, stream>>>(
            B0, Z, 0, nullptr, target, mask, 1, acc + 2,
            B0, Z, 0, nullptr, target, mask, 1, acc + 2);
    }

    final_kernel<<<1, 1, 0, stream>>>(acc, out);
}